// Round 5
// baseline (97.217 us; speedup 1.0000x reference)
//
#include <hip/hip_runtime.h>

// out = sign(x) * F(|x|);  F = 16-step spiking recurrence.
// Divide by (|v|+1) > 0 never changes sign -> z_t = (v_t > T_t).
// Interval analysis proves z=1 always at t = 0,2,3,6,11,13 (margins >= 0.5).
//
// Correctness split:
//  - v-chain: BIT-EXACT to numpy reference (each update = one fl op identical
//    to reference's v - z*h). A 1-ulp drift would flip decisions for ~5 of
//    67M samples -> error ~0.5 >> 2.2e-2 threshold. Untouched.
//  - acc-chain: freely reorderable (reassociation error ~1e-6 << threshold).
//    All 6 unconditional d's folded into C0 = 1.21686509; 10 conditional fmas.

typedef float vfloat4 __attribute__((ext_vector_type(4)));

__device__ __forceinline__ float run16(float xval) {
    float v = __builtin_fabsf(xval);
    // ---- v-chain + decisions (bit-exact, reference order) ----
    v = v - 0.06285988f;                         // t=1
    float z1 = (v > 1.2887092f) ? 1.0f : 0.0f;
    v = __builtin_fmaf(z1, -0.26102483f, v);     // t=2 (z=1 always)
    v = v + 0.37457255f;                         // t=3 (z=1 always, h<0)
    v = v - 0.3718868f;                          // t=4
    float z4 = (v > 1.1932085f) ? 1.0f : 0.0f;
    v = __builtin_fmaf(z4, -0.37248886f, v);     // t=5
    float z5 = (v > 2.9062123f) ? 1.0f : 0.0f;
    v = __builtin_fmaf(z5, -0.63687307f, v);     // t=6 (z=1 always)
    v = v + 0.92578804f;                         // t=7 (h<0)
    float z7 = (v > 1.9449068f) ? 1.0f : 0.0f;
    v = __builtin_fmaf(z7, -1.9272704f, v);      // t=8
    float z8 = (v > 0.6202121f) ? 1.0f : 0.0f;
    v = __builtin_fmaf(z8, -0.7057378f, v);      // t=9
    float z9 = (v > 0.41550368f) ? 1.0f : 0.0f;
    v = __builtin_fmaf(z9, -0.33205885f, v);     // t=10
    float z10 = (v > 0.6942196f) ? 1.0f : 0.0f;
    v = __builtin_fmaf(z10, -1.1465814f, v);     // t=11 (z=1 always)
    v = v + 1.2022963f;                          // t=12 (h<0)
    float z12 = (v > 2.0298457f) ? 1.0f : 0.0f;
    v = __builtin_fmaf(z12, -1.5285196f, v);     // t=13 (z=1 always)
    v = v - 0.6882014f;                          // t=14
    float z14 = (v > 1.0268241f) ? 1.0f : 0.0f;
    v = __builtin_fmaf(z14, -1.6742821f, v);     // t=15
    float z15 = (v > 0.6855806f) ? 1.0f : 0.0f;

    // ---- acc-chain (reorderable): C0 = d0+d2+d3+d6+d11+d13 ----
    float acc = 1.21686509f;
    acc = __builtin_fmaf(z1,  -0.15619771f, acc);
    acc = __builtin_fmaf(z4,  -0.17966147f, acc);
    acc = __builtin_fmaf(z5,  -0.05126573f, acc);
    acc = __builtin_fmaf(z7,  -0.3483371f,  acc);
    acc = __builtin_fmaf(z8,  -0.12764367f, acc);
    acc = __builtin_fmaf(z9,  -0.05997599f, acc);
    acc = __builtin_fmaf(z10, -0.06374894f, acc);
    acc = __builtin_fmaf(z12, -0.05318592f, acc);
    acc = __builtin_fmaf(z14, -0.03889612f, acc);
    acc = __builtin_fmaf(z15, -0.02578991f, acc);

    // acc * sign(x): flip sign bit (xor), force 0 when x == +/-0
    unsigned int sbit = __float_as_uint(xval) & 0x80000000u;
    float r = __uint_as_float(__float_as_uint(acc) ^ sbit);
    return (xval == 0.0f) ? 0.0f : r;
}

constexpr int V = 8;  // float4 loads in flight per loop iteration (32 elems)

// Exact-division variant: no bounds checks (host guarantees n%4==0 and
// n4 % (stride*V) == 0).
__global__ __launch_bounds__(256) void spike_exact(
    const float* __restrict__ x, float* __restrict__ out, int n4)
{
    const vfloat4* __restrict__ x4 = (const vfloat4*)x;
    vfloat4* __restrict__ o4 = (vfloat4*)out;

    const int tid = blockIdx.x * blockDim.x + threadIdx.x;
    const int stride = gridDim.x * blockDim.x;

    for (int i = tid; i < n4; i += stride * V) {
        vfloat4 in[V];
#pragma unroll
        for (int k = 0; k < V; ++k) in[k] = x4[i + k * stride];
#pragma unroll
        for (int k = 0; k < V; ++k) {
            vfloat4 r;
            r.x = run16(in[k].x);
            r.y = run16(in[k].y);
            r.z = run16(in[k].z);
            r.w = run16(in[k].w);
            __builtin_nontemporal_store(r, &o4[i + k * stride]);
        }
    }
}

// Guarded fallback for arbitrary n.
__global__ __launch_bounds__(256) void spike_guarded(
    const float* __restrict__ x, float* __restrict__ out, int n4, int n)
{
    const vfloat4* __restrict__ x4 = (const vfloat4*)x;
    vfloat4* __restrict__ o4 = (vfloat4*)out;

    const int tid = blockIdx.x * blockDim.x + threadIdx.x;
    const int stride = gridDim.x * blockDim.x;

    for (int i = tid; i < n4; i += stride * V) {
#pragma unroll
        for (int k = 0; k < V; ++k) {
            int idx = i + k * stride;
            if (idx < n4) {
                vfloat4 in = x4[idx];
                vfloat4 r;
                r.x = run16(in.x);
                r.y = run16(in.y);
                r.z = run16(in.z);
                r.w = run16(in.w);
                __builtin_nontemporal_store(r, &o4[idx]);
            }
        }
    }
    const int tail_start = n4 * 4;
    for (int i = tail_start + tid; i < n; i += stride) {
        out[i] = run16(x[i]);
    }
}

extern "C" void kernel_launch(void* const* d_in, const int* in_sizes, int n_in,
                              void* d_out, int out_size, void* d_ws, size_t ws_size,
                              hipStream_t stream) {
    const float* x = (const float*)d_in[0];
    float* out = (float*)d_out;

    const int n = in_sizes[0];
    const int n4 = n / 4;

    int blocks = 4096;
    int need = (n4 + 255) / 256;
    if (need < blocks) blocks = (need > 0) ? need : 1;
    const long long stride = (long long)blocks * 256;

    if ((n % 4) == 0 && (n4 % (stride * V)) == 0) {
        // Bench shape: n4 = 2^24, stride = 2^20, V=8 -> 2 exact iterations.
        spike_exact<<<blocks, 256, 0, stream>>>(x, out, n4);
    } else {
        spike_guarded<<<blocks, 256, 0, stream>>>(x, out, n4, n);
    }
}

// Round 6
// 82.462 us; speedup vs baseline: 1.1789x; 1.1789x over previous
//
#include <hip/hip_runtime.h>

// out = sign(x) * F(|x|);  F = 16-step spiking recurrence.
// Divide by (|v|+1) > 0 never changes sign -> z_t = (v_t > T_t).
// Interval analysis proves z=1 always at t = 0,2,3,6,11,13 (margins >= 0.5).
//
// Correctness split:
//  - v-chain: BIT-EXACT to numpy reference (each update = one fl op identical
//    to reference's v - z*h). Untouched.
//  - acc-chain: reorderable (verified absmax 0.0 in R5). Unconditional d's
//    folded into C0 = 1.21686509; 10 conditional fmas remain.

typedef float vfloat4 __attribute__((ext_vector_type(4)));

__device__ __forceinline__ float run16(float xval) {
    float v = __builtin_fabsf(xval);
    // ---- v-chain + decisions (bit-exact, reference order) ----
    v = v - 0.06285988f;                         // t=1
    float z1 = (v > 1.2887092f) ? 1.0f : 0.0f;
    v = __builtin_fmaf(z1, -0.26102483f, v);     // t=2 (z=1 always)
    v = v + 0.37457255f;                         // t=3 (z=1 always, h<0)
    v = v - 0.3718868f;                          // t=4
    float z4 = (v > 1.1932085f) ? 1.0f : 0.0f;
    v = __builtin_fmaf(z4, -0.37248886f, v);     // t=5
    float z5 = (v > 2.9062123f) ? 1.0f : 0.0f;
    v = __builtin_fmaf(z5, -0.63687307f, v);     // t=6 (z=1 always)
    v = v + 0.92578804f;                         // t=7 (h<0)
    float z7 = (v > 1.9449068f) ? 1.0f : 0.0f;
    v = __builtin_fmaf(z7, -1.9272704f, v);      // t=8
    float z8 = (v > 0.6202121f) ? 1.0f : 0.0f;
    v = __builtin_fmaf(z8, -0.7057378f, v);      // t=9
    float z9 = (v > 0.41550368f) ? 1.0f : 0.0f;
    v = __builtin_fmaf(z9, -0.33205885f, v);     // t=10
    float z10 = (v > 0.6942196f) ? 1.0f : 0.0f;
    v = __builtin_fmaf(z10, -1.1465814f, v);     // t=11 (z=1 always)
    v = v + 1.2022963f;                          // t=12 (h<0)
    float z12 = (v > 2.0298457f) ? 1.0f : 0.0f;
    v = __builtin_fmaf(z12, -1.5285196f, v);     // t=13 (z=1 always)
    v = v - 0.6882014f;                          // t=14
    float z14 = (v > 1.0268241f) ? 1.0f : 0.0f;
    v = __builtin_fmaf(z14, -1.6742821f, v);     // t=15
    float z15 = (v > 0.6855806f) ? 1.0f : 0.0f;

    // ---- acc-chain (reorderable): C0 = d0+d2+d3+d6+d11+d13 ----
    float acc = 1.21686509f;
    acc = __builtin_fmaf(z1,  -0.15619771f, acc);
    acc = __builtin_fmaf(z4,  -0.17966147f, acc);
    acc = __builtin_fmaf(z5,  -0.05126573f, acc);
    acc = __builtin_fmaf(z7,  -0.3483371f,  acc);
    acc = __builtin_fmaf(z8,  -0.12764367f, acc);
    acc = __builtin_fmaf(z9,  -0.05997599f, acc);
    acc = __builtin_fmaf(z10, -0.06374894f, acc);
    acc = __builtin_fmaf(z12, -0.05318592f, acc);
    acc = __builtin_fmaf(z14, -0.03889612f, acc);
    acc = __builtin_fmaf(z15, -0.02578991f, acc);

    // acc * sign(x): flip sign bit (xor), force 0 when x == +/-0
    unsigned int sbit = __float_as_uint(xval) & 0x80000000u;
    float r = __uint_as_float(__float_as_uint(acc) ^ sbit);
    return (xval == 0.0f) ? 0.0f : r;
}

// One-shot kernel: each block owns a contiguous 1024-float4 (16 KB) chunk;
// thread t does 4 coalesced float4s at base + t + k*256. No loop-carried
// state -> block churn provides the pipelining; short blocks shrink the
// drain tail and keep DRAM page locality per block.
__global__ __launch_bounds__(256) void spike_oneshot(
    const float* __restrict__ x, float* __restrict__ out)
{
    const vfloat4* __restrict__ x4 = (const vfloat4*)x;
    vfloat4* __restrict__ o4 = (vfloat4*)out;

    const int base = blockIdx.x * 1024 + threadIdx.x;

    vfloat4 in[4];
#pragma unroll
    for (int k = 0; k < 4; ++k) in[k] = x4[base + k * 256];
#pragma unroll
    for (int k = 0; k < 4; ++k) {
        vfloat4 r;
        r.x = run16(in[k].x);
        r.y = run16(in[k].y);
        r.z = run16(in[k].z);
        r.w = run16(in[k].w);
        __builtin_nontemporal_store(r, &o4[base + k * 256]);
    }
}

// Guarded grid-stride fallback for arbitrary n.
__global__ __launch_bounds__(256) void spike_guarded(
    const float* __restrict__ x, float* __restrict__ out, int n4, int n)
{
    const vfloat4* __restrict__ x4 = (const vfloat4*)x;
    vfloat4* __restrict__ o4 = (vfloat4*)out;

    const int tid = blockIdx.x * blockDim.x + threadIdx.x;
    const int stride = gridDim.x * blockDim.x;

    for (int i = tid; i < n4; i += stride) {
        vfloat4 in = x4[i];
        vfloat4 r;
        r.x = run16(in.x);
        r.y = run16(in.y);
        r.z = run16(in.z);
        r.w = run16(in.w);
        __builtin_nontemporal_store(r, &o4[i]);
    }
    const int tail_start = n4 * 4;
    for (int i = tail_start + tid; i < n; i += stride) {
        out[i] = run16(x[i]);
    }
}

extern "C" void kernel_launch(void* const* d_in, const int* in_sizes, int n_in,
                              void* d_out, int out_size, void* d_ws, size_t ws_size,
                              hipStream_t stream) {
    const float* x = (const float*)d_in[0];
    float* out = (float*)d_out;

    const int n = in_sizes[0];
    const int n4 = n / 4;

    if ((n % 4) == 0 && (n4 % 1024) == 0) {
        // Bench shape: n4 = 2^24 -> 16384 one-shot blocks.
        const int blocks = n4 / 1024;
        spike_oneshot<<<blocks, 256, 0, stream>>>(x, out);
    } else {
        int blocks = 2048;
        int need = (n4 + 255) / 256;
        if (need < blocks) blocks = (need > 0) ? need : 1;
        spike_guarded<<<blocks, 256, 0, stream>>>(x, out, n4, n);
    }
}